// Round 6
// baseline (8044.492 us; speedup 1.0000x reference)
//
#include <hip/hip_runtime.h>
#include <math.h>

#define NT     365
#define NGRID  3000
#define NX     20
#define H      256
#define CPB    15
#define NBLK   (NGRID/CPB)     // 200 blocks, 1 per CU
#define THREADS 1024           // 16 waves, 4 per SIMD

// packed weight sizes (ushorts)
// wpk HI-ONLY, pi-ordered: [g 16][pi 16][q 4][lane 64][e 8]
//   pi 0..7  = h-kaps  (k 256..511, w_hh) -> consumed in G1
//   pi 8..15 = x-kaps  (k 0..255,  w_ih) -> consumed in G2
#define WPK_US   (16*16*4*64*8)   // 524,288
#define WPKIN_US (16*2*64*8)      // 16,384

typedef short v8s __attribute__((ext_vector_type(8)));
typedef float v4f __attribute__((ext_vector_type(4)));
#define MFMA_BF16 __builtin_amdgcn_mfma_f32_16x16x32_bf16

__device__ __forceinline__ unsigned short f2bf(float f) {
    unsigned int u = __float_as_uint(f);
    u += 0x7fffu + ((u >> 16) & 1u);          // RTNE
    return (unsigned short)(u >> 16);
}
__device__ __forceinline__ float bf2f(unsigned short h) {
    return __uint_as_float(((unsigned int)h) << 16);
}
__device__ __forceinline__ float sigm(float x)  { return 1.0f / (1.0f + __expf(-x)); }
__device__ __forceinline__ float tanh_f(float x){ return 2.0f * sigm(2.0f * x) - 1.0f; }

// ---------------- weight pre-pack ----------------
__global__ void prep_kernel(const float* __restrict__ w_in,
                            const float* __restrict__ w_ih,
                            const float* __restrict__ w_hh,
                            const float* __restrict__ b_ih,
                            const float* __restrict__ b_hh,
                            unsigned short* __restrict__ wpk,
                            unsigned short* __restrict__ wpkin,
                            float* __restrict__ bsum) {
    int idx = blockIdx.x * 256 + threadIdx.x;
    if (idx < WPK_US) {
        int e    = idx & 7;
        int lane = (idx >> 3) & 63;
        int q    = (idx >> 9) & 3;
        int gk   = idx >> 11;            // 0..255
        int pi   = gk & 15, g = gk >> 4;
        int kap  = (pi < 8) ? pi + 8 : pi - 8;   // pi 0..7 = h, 8..15 = x
        int k = kap * 32 + ((lane >> 4) << 3) + e;
        int j = q * 256 + g * 16 + (lane & 15);
        float wv = (k < 256) ? w_ih[j * 256 + k] : w_hh[j * 256 + (k - 256)];
        wpk[idx] = f2bf(wv);             // hi only
    }
    if (idx < WPKIN_US) {
        int e    = idx & 7;
        int lane = (idx >> 3) & 63;
        int d    = (idx >> 9) & 1;
        int tau  = idx >> 10;            // 0..15
        int k = ((lane >> 4) << 3) + e;
        int n = tau * 16 + (lane & 15);
        float wv = (k < NX + 1) ? w_in[n * (NX + 1) + k] : 0.0f;
        unsigned short hi = f2bf(wv);
        wpkin[idx] = d ? f2bf(wv - bf2f(hi)) : hi;
    }
    if (idx < 4 * H) bsum[idx] = b_ih[idx] + b_hh[idx];
}

// ---------------- main persistent LSTM ----------------
// R14: weights NEVER touch VGPRs.  Five rounds of evidence: arch-VGPR budget
// at 16 waves/block is ~64; every register-resident weight scheme spilled
// (VGPR pinned at 64, WRITE/FETCH blowups).  Switch to the verified m201
// pattern: global_load_lds DMA -> 3-slot rotating LDS buffer (96 KB),
// ds_read_b128 just before MFMA, hand-counted vmcnt(N), raw lgkm barriers.
//  - 32 half-pi stream units/step (2 KB/wave = 2 gload_lds each), 2-ahead.
//  - pipeline resets per step: next step's halves 0,1,2 issued at E-start,
//    refill hides under E+P5+P1'+X (no consumption there).
//  - x/y prefetch made wave-uniform (clamped unconditional) so vmcnt
//    counts are identical across waves.
//  - no weight persistence: stream 1 MB/step via L2 (~7.4 us/step floor).
__global__ __attribute__((amdgpu_flat_work_group_size(THREADS, THREADS),
                          amdgpu_waves_per_eu(4, 4)))
void lstm_main(const float* __restrict__ x,
               const float* __restrict__ y,
               const float* __restrict__ b_in,
               const float* __restrict__ w_out,
               const float* __restrict__ b_out,
               const unsigned short* __restrict__ wpk,
               const unsigned short* __restrict__ wpkin,
               const float* __restrict__ bsum,
               float* __restrict__ out) {
    // fragment-major activation buffers: [pi][lane*8+e], lane = qp*16 + m
    __shared__ __align__(16) unsigned short Agh[16][512];   // 16 KB
    __shared__ __align__(16) unsigned short Agl[16][512];   // 16 KB
    __shared__ __align__(16) unsigned short Xh[512];        // 1 KB
    __shared__ __align__(16) unsigned short Xl[512];        // 1 KB
    __shared__ __align__(16) unsigned short Bst[3][16][1024]; // 96 KB stage
    __shared__ float y_part[16][16];
    // total = 131 KB -> 1 block/CU

    const int tid  = threadIdx.x;
    const int w    = tid >> 6;          // wave 0..15; owns output group g = w
    const int lane = tid & 63;
    const int col  = lane & 15;
    const int quad = lane >> 4;
    const int g0   = blockIdx.x * CPB;

    // per-wave constants: lane owns hidden index jh = w*16 + col
    const int   jh   = w * 16 + col;
    const float b_i  = bsum[jh];
    const float b_f  = bsum[256 + jh];
    const float b_g  = bsum[512 + jh];
    const float b_o  = bsum[768 + jh];
    const float wo   = w_out[jh];
    const float bi_x = b_in[jh];
    const float bout = b_out[0];
    const int   hs   = jh >> 5;                   // 0..7
    const int   pi_x = 8 + hs;                    // x0 write plane (8..15)
    const int   pi_h = hs;                        // h write plane (0..7)
    const int   qp_w = (jh >> 3) & 3;
    const int   e_w  = jh & 7;
    // per-lane global byte base of this wave's weight slice (64 KB/wave)
    const char* wbl = (const char*)wpk + (w << 16) + (lane << 4);
    const unsigned short* bx_hi = wpkin + (w * 2 + 0) * 512 + lane * 8;
    const unsigned short* bx_lo = wpkin + (w * 2 + 1) * 512 + lane * 8;

    // clamped wave-uniform prefetch indices (every wave issues both loads)
    const int ixc = (tid < CPB * NX) ? tid : (CPB * NX - 1);
    const int iyc = (tid < CPB)      ? tid : (CPB - 1);

    // raw barrier: orders LDS (lgkm) only; VMEM stays in flight across it.
#define BAR()                                                           \
    do {                                                                \
        asm volatile("s_waitcnt lgkmcnt(0)" ::: "memory");              \
        __builtin_amdgcn_sched_barrier(0);                              \
        __builtin_amdgcn_s_barrier();                                   \
        __builtin_amdgcn_sched_barrier(0);                              \
    } while (0)

#define WAITV(N) asm volatile("s_waitcnt vmcnt(" #N ")" ::: "memory")

    // stage half-unit U (byte offset U*2048 in this wave's slice) into SLOT
#define STAGE(U, SLOT)                                                  \
    do {                                                                \
        __builtin_amdgcn_global_load_lds(                               \
            (const unsigned int*)(wbl + (U) * 2048),                    \
            (unsigned int*)&Bst[SLOT][w][0], 16, 0, 0);                 \
        __builtin_amdgcn_global_load_lds(                               \
            (const unsigned int*)(wbl + (U) * 2048 + 1024),             \
            (unsigned int*)&Bst[SLOT][w][512], 16, 0, 0);               \
    } while (0)

    // consume one half from SLOT: even half -> acc0/acc1, odd -> acc2/acc3
#define GH_EVEN(PI, SLOT)                                               \
    do {                                                                \
        Ah = *(const v8s*)&Agh[PI][lane * 8];                           \
        Al = *(const v8s*)&Agl[PI][lane * 8];                           \
        v8s B0 = *(const v8s*)&Bst[SLOT][w][lane * 8];                  \
        v8s B1 = *(const v8s*)&Bst[SLOT][w][512 + lane * 8];            \
        acc0 = MFMA_BF16(Ah, B0, acc0, 0, 0, 0);                        \
        acc0 = MFMA_BF16(Al, B0, acc0, 0, 0, 0);                        \
        acc1 = MFMA_BF16(Ah, B1, acc1, 0, 0, 0);                        \
        acc1 = MFMA_BF16(Al, B1, acc1, 0, 0, 0);                        \
    } while (0)
#define GH_ODD(PI, SLOT)                                                \
    do {                                                                \
        v8s B2 = *(const v8s*)&Bst[SLOT][w][lane * 8];                  \
        v8s B3 = *(const v8s*)&Bst[SLOT][w][512 + lane * 8];            \
        acc2 = MFMA_BF16(Ah, B2, acc2, 0, 0, 0);                        \
        acc2 = MFMA_BF16(Al, B2, acc2, 0, 0, 0);                        \
        acc3 = MFMA_BF16(Ah, B3, acc3, 0, 0, 0);                        \
        acc3 = MFMA_BF16(Al, B3, acc3, 0, 0, 0);                        \
    } while (0)

    // ---- prologue: x/y for t=0, first 3 stage units, LDS zero-init
    float xv = x[(size_t)g0 * NX + ixc];
    float yv = y[(size_t)g0 + iyc];
    STAGE(0, 0); STAGE(1, 1); STAGE(2, 2);

    const v8s bxh = *(const v8s*)bx_hi;     // per-wave constant across steps
    const v8s bxl = *(const v8s*)bx_lo;

    {
        unsigned int* p;
        p = (unsigned int*)&Agh[0][0];
        for (int i = tid; i < 16 * 256; i += THREADS) p[i] = 0u;
        p = (unsigned int*)&Agl[0][0];
        for (int i = tid; i < 16 * 256; i += THREADS) p[i] = 0u;
        if (tid < 256) ((unsigned int*)&Xh[0])[tid] = 0u;
        if (tid < 256) ((unsigned int*)&Xl[0])[tid] = 0u;
    }
    float c_st[4];
    #pragma unroll
    for (int r = 0; r < 4; ++r) c_st[r] = 0.0f;
    BAR();      // zero-init visible (lgkm only; staged loads stay in flight)

    v8s Ah, Al;

    #pragma unroll 1
    for (int t = 0; t < NT; ++t) {
        // ---- P1': stage xcat from prefetched regs (pure LDS writes)
        if (tid < CPB * NX) {
            float v  = xv;
            int cell = tid / NX;
            int k    = tid - cell * NX;
            int pos  = (((k >> 3) << 4) + cell) * 8 + (k & 7);
            unsigned short hi = f2bf(v);
            Xh[pos] = hi;
            Xl[pos] = f2bf(v - bf2f(hi));
        }
        if (tid < CPB) {
            if (!__builtin_isnan(yv)) {
                int pos = (2 * 16 + tid) * 8 + 4;     // k = 20
                unsigned short hi = f2bf(yv);
                Xh[pos] = hi;
                Xl[pos] = f2bf(yv - bf2f(hi));
            }
        }
        BAR();                                         // barrier A

        // ---- X: x0 = relu(xcat @ w_in^T + b_in); writes planes 8..15 only
        {
            v8s xah = *(const v8s*)&Xh[lane * 8];
            v8s xal = *(const v8s*)&Xl[lane * 8];
            v4f xacc = {0.0f, 0.0f, 0.0f, 0.0f};
            xacc = MFMA_BF16(xah, bxh, xacc, 0, 0, 0);
            xacc = MFMA_BF16(xah, bxl, xacc, 0, 0, 0);
            xacc = MFMA_BF16(xal, bxh, xacc, 0, 0, 0);
            #pragma unroll
            for (int r = 0; r < 4; ++r) {
                int cell = quad * 4 + r;
                if (cell < CPB) {
                    float v = fmaxf(xacc[r] + bi_x, 0.0f);
                    unsigned short hi = f2bf(v);
                    int pos = (qp_w * 16 + cell) * 8 + e_w;
                    Agh[pi_x][pos] = hi;
                    Agl[pi_x][pos] = f2bf(v - bf2f(hi));
                }
            }
        }
        // no barrier: G1 reads planes 0..7 -- disjoint from X's writes

        // ---- G1: h-planes pi 0..7 (halves 0..15), staged pipeline
        v4f acc0 = {0.0f, 0.0f, 0.0f, 0.0f};
        v4f acc1 = {0.0f, 0.0f, 0.0f, 0.0f};
        v4f acc2 = {0.0f, 0.0f, 0.0f, 0.0f};
        v4f acc3 = {0.0f, 0.0f, 0.0f, 0.0f};

        WAITV(4); GH_EVEN(0, 0); STAGE(3, 0);
        WAITV(4); GH_ODD(0, 1);  STAGE(4, 1);
        WAITV(4); GH_EVEN(1, 2); STAGE(5, 2);
        WAITV(4); GH_ODD(1, 0);  STAGE(6, 0);
        WAITV(4); GH_EVEN(2, 1); STAGE(7, 1);
        WAITV(4); GH_ODD(2, 2);  STAGE(8, 2);
        WAITV(4); GH_EVEN(3, 0); STAGE(9, 0);
        WAITV(4); GH_ODD(3, 1);  STAGE(10, 1);
        WAITV(4); GH_EVEN(4, 2); STAGE(11, 2);
        WAITV(4); GH_ODD(4, 0);  STAGE(12, 0);
        WAITV(4); GH_EVEN(5, 1); STAGE(13, 1);
        WAITV(4); GH_ODD(5, 2);  STAGE(14, 2);
        WAITV(4); GH_EVEN(6, 0); STAGE(15, 0);
        WAITV(4); GH_ODD(6, 1);  STAGE(16, 1);
        WAITV(4); GH_EVEN(7, 2); STAGE(17, 2);
        WAITV(4); GH_ODD(7, 0);  STAGE(18, 0);
        BAR();                                         // barrier B

        // ---- prefetch x/y for t+1 (wave-uniform; flies across barrier C)
        {
            const int tn = (t + 1 < NT) ? (t + 1) : t;
            xv = x[((size_t)tn * NGRID + g0) * NX + ixc];
            yv = y[(size_t)tn * NGRID + g0 + iyc];
        }

        // ---- G2: x-planes pi 8..15 (halves 16..31), x0 ordered by barrier B
        WAITV(6); GH_EVEN(8, 1);  STAGE(19, 1);
        WAITV(6); GH_ODD(8, 2);   STAGE(20, 2);
        WAITV(6); GH_EVEN(9, 0);  STAGE(21, 0);
        WAITV(6); GH_ODD(9, 1);   STAGE(22, 1);
        WAITV(6); GH_EVEN(10, 2); STAGE(23, 2);
        WAITV(6); GH_ODD(10, 0);  STAGE(24, 0);
        WAITV(6); GH_EVEN(11, 1); STAGE(25, 1);
        WAITV(6); GH_ODD(11, 2);  STAGE(26, 2);
        WAITV(6); GH_EVEN(12, 0); STAGE(27, 0);
        WAITV(6); GH_ODD(12, 1);  STAGE(28, 1);
        WAITV(6); GH_EVEN(13, 2); STAGE(29, 2);
        WAITV(6); GH_ODD(13, 0);  STAGE(30, 0);
        WAITV(6); GH_EVEN(14, 1); STAGE(31, 1);
        WAITV(6); GH_ODD(14, 2);
        WAITV(4); GH_EVEN(15, 0);
        WAITV(2); GH_ODD(15, 1);

        // ---- E: refill pipeline for next step, then pointwise LSTM
        STAGE(0, 0); STAGE(1, 1); STAGE(2, 2);   // next step's halves 0..2
        {
            float yp[4];
            #pragma unroll
            for (int r = 0; r < 4; ++r) {
                int cell = quad * 4 + r;
                float iv = acc0[r] + b_i;
                float fv = acc1[r] + b_f;
                float gv = acc2[r] + b_g;
                float ov = acc3[r] + b_o;
                float c  = fmaf(sigm(fv), c_st[r], sigm(iv) * tanh_f(gv));
                c_st[r]  = c;
                float h  = sigm(ov) * tanh_f(c);
                yp[r] = 0.0f;
                if (cell < CPB) {
                    unsigned short hi = f2bf(h);
                    int pos = (qp_w * 16 + cell) * 8 + e_w;
                    Agh[pi_h][pos] = hi;
                    Agl[pi_h][pos] = f2bf(h - bf2f(hi));
                    yp[r] = h * wo;
                }
            }
            #pragma unroll
            for (int r = 0; r < 4; ++r) {
                float p = yp[r];
                p += __shfl_xor(p, 1);
                p += __shfl_xor(p, 2);
                p += __shfl_xor(p, 4);
                p += __shfl_xor(p, 8);
                if (col == 0)
                    y_part[w][quad * 4 + r] = p;
            }
        }
        BAR();                                         // barrier C

        // ---- P5: finalize y, store, feed back into xcat k=20
        if (tid < CPB) {
            float yfin = bout;
            #pragma unroll
            for (int w2 = 0; w2 < 16; ++w2) yfin += y_part[w2][tid];
            out[(size_t)t * NGRID + g0 + tid] = yfin;
            int pos = (2 * 16 + tid) * 8 + 4;             // k = 20
            unsigned short hi = f2bf(yfin);
            Xh[pos] = hi;
            Xl[pos] = f2bf(yfin - bf2f(hi));
        }
    }
}

extern "C" void kernel_launch(void* const* d_in, const int* in_sizes, int n_in,
                              void* d_out, int out_size, void* d_ws, size_t ws_size,
                              hipStream_t stream) {
    const float* x     = (const float*)d_in[0];
    const float* y     = (const float*)d_in[1];
    const float* w_in  = (const float*)d_in[2];
    const float* b_in  = (const float*)d_in[3];
    const float* w_ih  = (const float*)d_in[4];
    const float* b_ih  = (const float*)d_in[5];
    const float* w_hh  = (const float*)d_in[6];
    const float* b_hh  = (const float*)d_in[7];
    const float* w_out = (const float*)d_in[8];
    const float* b_out = (const float*)d_in[9];

    unsigned short* wpk   = (unsigned short*)d_ws;
    unsigned short* wpkin = wpk + WPK_US;
    float*          bsum  = (float*)(wpkin + WPKIN_US);
    float*          out   = (float*)d_out;

    prep_kernel<<<(WPK_US + 255) / 256, 256, 0, stream>>>(
        w_in, w_ih, w_hh, b_ih, b_hh, wpk, wpkin, bsum);
    lstm_main<<<NBLK, THREADS, 0, stream>>>(
        x, y, b_in, w_out, b_out, wpk, wpkin, bsum, out);
}